// Round 4
// baseline (203.128 us; speedup 1.0000x reference)
//
#include <hip/hip_runtime.h>
#include <math.h>

#define SAMPLE_RATE 44100.0
#define R_PARAM 0.5
#define F_PARAM 1000.0

typedef float f32x4 __attribute__((ext_vector_type(4)));

// ---------------------------------------------------------------------------
// Prologue: single thread builds the combined affine map from the 4 scalars.
// ws layout (floats): [0..15] Mc = M_inv@M_fwd (row-major),
//                     [16..19] va = M_inv@b_a, [20..23] vb = M_inv@b_1ma,
//                     [24] gain
// ---------------------------------------------------------------------------
__device__ void inv4x4(const double A[4][4], double Ainv[4][4]) {
    double M[4][8];
    for (int i = 0; i < 4; ++i) {
        for (int j = 0; j < 4; ++j) { M[i][j] = A[i][j]; M[i][4 + j] = (i == j) ? 1.0 : 0.0; }
    }
    for (int col = 0; col < 4; ++col) {
        int p = col;
        for (int r = col + 1; r < 4; ++r)
            if (fabs(M[r][col]) > fabs(M[p][col])) p = r;
        if (p != col)
            for (int j = 0; j < 8; ++j) { double t = M[col][j]; M[col][j] = M[p][j]; M[p][j] = t; }
        double d = 1.0 / M[col][col];
        for (int j = 0; j < 8; ++j) M[col][j] *= d;
        for (int r = 0; r < 4; ++r) {
            if (r == col) continue;
            double f = M[r][col];
            for (int j = 0; j < 8; ++j) M[r][j] -= f * M[col][j];
        }
    }
    for (int i = 0; i < 4; ++i)
        for (int j = 0; j < 4; ++j) Ainv[i][j] = M[i][4 + j];
}

__global__ void moog_prologue(const float* __restrict__ gf,
                              const float* __restrict__ gr,
                              const float* __restrict__ gain,
                              const float* __restrict__ alpha,
                              float* __restrict__ ws) {
    const double k  = 1.0 / SAMPLE_RATE;
    const double w  = 2.0 * M_PI * (double)gf[0] * F_PARAM;
    const double grv = (double)gr[0];
    const double al  = (double)alpha[0];
    const double gn  = (double)gain[0];

    double A[4][4] = {
        { -w, 0.0, 0.0, -4.0 * w * grv * R_PARAM },
        {  w,  -w, 0.0, 0.0 },
        { 0.0,  w,  -w, 0.0 },
        { 0.0, 0.0,  w,  -w }
    };

    double kA2[4][4];
    for (int i = 0; i < 4; ++i)
        for (int j = 0; j < 4; ++j) kA2[i][j] = 0.5 * k * A[i][j];

    double Mlhs[4][4];
    for (int i = 0; i < 4; ++i)
        for (int j = 0; j < 4; ++j)
            Mlhs[i][j] = ((i == j) ? 1.0 : 0.0) - kA2[i][j] * al;

    double Minv[4][4];
    inv4x4(Mlhs, Minv);

    double Mfwd[4][4];
    for (int i = 0; i < 4; ++i)
        for (int j = 0; j < 4; ++j)
            Mfwd[i][j] = ((i == j) ? 1.0 : 0.0) + kA2[i][j] * (2.0 - al);

    double Mc[4][4];
    for (int i = 0; i < 4; ++i)
        for (int j = 0; j < 4; ++j) {
            double s = 0.0;
            for (int m = 0; m < 4; ++m) s += Minv[i][m] * Mfwd[m][j];
            Mc[i][j] = s;
        }

    double kb2_0 = 0.5 * k * w;
    double ba0  = kb2_0 * al;
    double b1m0 = kb2_0 * (1.0 - 0.5 * al);

    for (int i = 0; i < 4; ++i) {
        for (int j = 0; j < 4; ++j) ws[4 * i + j] = (float)Mc[i][j];
        ws[16 + i] = (float)(Minv[i][0] * ba0);
        ws[20 + i] = (float)(Minv[i][0] * b1m0);
    }
    ws[24] = (float)gn;
}

// ---------------------------------------------------------------------------
// v4 main: fill-style streaming. Few blocks (2 per CU), each block owns a
// contiguous chunk and walks it sequentially, 1024 samples per loop body.
// Loads and stores are grouped per stream so each block issues multi-KB
// sequential bursts per stream (HBM row locality). Regular (cached) stores.
// out layout: [0,B) = y_n ; [B,5B) = x_n ; [5B,6B) = u_n copy
// Requires B % 4 == 0 for the f32x4 view of the x output.
// ---------------------------------------------------------------------------
__global__ __launch_bounds__(256) void moog_main_v4(
        const float* __restrict__ u_n,
        const f32x4* __restrict__ x4,
        const float* __restrict__ u_n1,
        const float* __restrict__ ws,
        float* __restrict__ out,
        int B, int S) {
    __shared__ float c[25];
    int t = threadIdx.x;
    if (t < 25) c[t] = ws[t];
    __syncthreads();

    float* oy = out;
    f32x4* ox = (f32x4*)(out + (size_t)B);
    float* ou = out + 5 * (size_t)B;

    size_t base = (size_t)blockIdx.x * (size_t)S;
    size_t end  = base + (size_t)S;
    if (base >= (size_t)B) return;
    if (end > (size_t)B) end = (size_t)B;

    for (size_t j0 = base; j0 < end; j0 += 1024) {
        size_t s0 = j0 + (size_t)t;

        float u[4];
        f32x4 x[4];
        float u1[4];
        bool  v[4];

        // ---- load phase: grouped per stream for long sequential bursts ----
        #pragma unroll
        for (int k = 0; k < 4; ++k) {
            size_t s = s0 + (size_t)(k << 8);
            v[k] = s < (size_t)B;
            if (v[k]) u[k] = u_n[s];
        }
        #pragma unroll
        for (int k = 0; k < 4; ++k) {
            size_t s = s0 + (size_t)(k << 8);
            if (v[k]) x[k] = x4[s];
        }
        #pragma unroll
        for (int k = 0; k < 4; ++k) {
            size_t s = s0 + (size_t)(k << 8);
            if (v[k]) u1[k] = u_n1[s];
        }

        // ---- compute (expression order identical to the verified kernel) ----
        float r0[4], r1[4], r2[4], r3[4];
        #pragma unroll
        for (int k = 0; k < 4; ++k) {
            if (v[k]) {
                r0[k] = c[0]  * x[k].x + c[1]  * x[k].y + c[2]  * x[k].z + c[3]  * x[k].w + c[16] * u[k] + c[20] * u1[k];
                r1[k] = c[4]  * x[k].x + c[5]  * x[k].y + c[6]  * x[k].z + c[7]  * x[k].w + c[17] * u[k] + c[21] * u1[k];
                r2[k] = c[8]  * x[k].x + c[9]  * x[k].y + c[10] * x[k].z + c[11] * x[k].w + c[18] * u[k] + c[22] * u1[k];
                r3[k] = c[12] * x[k].x + c[13] * x[k].y + c[14] * x[k].z + c[15] * x[k].w + c[19] * u[k] + c[23] * u1[k];
            }
        }

        // ---- store phase: grouped per stream ----
        #pragma unroll
        for (int k = 0; k < 4; ++k) {
            size_t s = s0 + (size_t)(k << 8);
            if (v[k]) oy[s] = c[24] * r3[k];
        }
        #pragma unroll
        for (int k = 0; k < 4; ++k) {
            size_t s = s0 + (size_t)(k << 8);
            if (v[k]) { f32x4 xv = {r0[k], r1[k], r2[k], r3[k]}; ox[s] = xv; }
        }
        #pragma unroll
        for (int k = 0; k < 4; ++k) {
            size_t s = s0 + (size_t)(k << 8);
            if (v[k]) ou[s] = u[k];
        }
    }
}

// ---------------------------------------------------------------------------
// Scalar fallback (the original verified kernel) for B % 4 != 0.
// ---------------------------------------------------------------------------
__global__ __launch_bounds__(256) void moog_main(
        const float*  __restrict__ u_n,
        const float4* __restrict__ x_n1,
        const float*  __restrict__ u_n1,
        const float*  __restrict__ ws,
        float* __restrict__ out,
        int B) {
    __shared__ float c[25];
    int t = threadIdx.x;
    if (t < 25) c[t] = ws[t];
    __syncthreads();

    int i = blockIdx.x * blockDim.x + t;
    if (i >= B) return;

    float4 x = x_n1[i];
    float u  = u_n[i];
    float u1 = u_n1[i];

    float r0 = c[0]  * x.x + c[1]  * x.y + c[2]  * x.z + c[3]  * x.w + c[16] * u + c[20] * u1;
    float r1 = c[4]  * x.x + c[5]  * x.y + c[6]  * x.z + c[7]  * x.w + c[17] * u + c[21] * u1;
    float r2 = c[8]  * x.x + c[9]  * x.y + c[10] * x.z + c[11] * x.w + c[18] * u + c[22] * u1;
    float r3 = c[12] * x.x + c[13] * x.y + c[14] * x.z + c[15] * x.w + c[19] * u + c[23] * u1;

    out[i] = c[24] * r3;
    float* ox = out + (size_t)B + 4 * (size_t)i;
    ox[0] = r0; ox[1] = r1; ox[2] = r2; ox[3] = r3;
    out[5 * (size_t)B + i] = u;
}

extern "C" void kernel_launch(void* const* d_in, const int* in_sizes, int n_in,
                              void* d_out, int out_size, void* d_ws, size_t ws_size,
                              hipStream_t stream) {
    const float* u_n   = (const float*)d_in[0];
    const float* x_n1  = (const float*)d_in[1];
    const float* u_n1  = (const float*)d_in[2];
    const float* gf    = (const float*)d_in[3];
    const float* gr    = (const float*)d_in[4];
    const float* gain  = (const float*)d_in[5];
    const float* alpha = (const float*)d_in[6];

    int B = in_sizes[0];
    float* ws = (float*)d_ws;

    moog_prologue<<<1, 1, 0, stream>>>(gf, gr, gain, alpha, ws);

    if ((B & 3) == 0) {
        const int grid = 512;                       // 2 blocks per CU
        // chunk per block, multiple of 1024 samples
        long long per = ((long long)B + (long long)grid * 1024 - 1) / ((long long)grid * 1024);
        int S = (int)(per * 1024);
        moog_main_v4<<<grid, 256, 0, stream>>>(u_n, (const f32x4*)x_n1, u_n1, ws,
                                               (float*)d_out, B, S);
    } else {
        int block = 256;
        int grid = (B + block - 1) / block;
        moog_main<<<grid, block, 0, stream>>>(u_n, (const float4*)x_n1, u_n1, ws,
                                              (float*)d_out, B);
    }
}

// Round 5
// 200.020 us; speedup vs baseline: 1.0155x; 1.0155x over previous
//
#include <hip/hip_runtime.h>
#include <math.h>

#define SAMPLE_RATE 44100.0
#define R_PARAM 0.5
#define F_PARAM 1000.0

typedef float f32x4 __attribute__((ext_vector_type(4)));

// ---------------------------------------------------------------------------
// Coefficient build (verbatim numerics from the verified prologue).
// Produces: c[0..15] Mc = M_inv@M_fwd, c[16..19] va, c[20..23] vb, c[24] gain
// ---------------------------------------------------------------------------
__device__ void inv4x4(const double A[4][4], double Ainv[4][4]) {
    double M[4][8];
    for (int i = 0; i < 4; ++i) {
        for (int j = 0; j < 4; ++j) { M[i][j] = A[i][j]; M[i][4 + j] = (i == j) ? 1.0 : 0.0; }
    }
    for (int col = 0; col < 4; ++col) {
        int p = col;
        for (int r = col + 1; r < 4; ++r)
            if (fabs(M[r][col]) > fabs(M[p][col])) p = r;
        if (p != col)
            for (int j = 0; j < 8; ++j) { double t = M[col][j]; M[col][j] = M[p][j]; M[p][j] = t; }
        double d = 1.0 / M[col][col];
        for (int j = 0; j < 8; ++j) M[col][j] *= d;
        for (int r = 0; r < 4; ++r) {
            if (r == col) continue;
            double f = M[r][col];
            for (int j = 0; j < 8; ++j) M[r][j] -= f * M[col][j];
        }
    }
    for (int i = 0; i < 4; ++i)
        for (int j = 0; j < 4; ++j) Ainv[i][j] = M[i][4 + j];
}

__device__ void build_coeffs(const float* __restrict__ gf,
                             const float* __restrict__ gr,
                             const float* __restrict__ gain,
                             const float* __restrict__ alpha,
                             float* __restrict__ c /* 25 floats (LDS ok) */) {
    const double k  = 1.0 / SAMPLE_RATE;
    const double w  = 2.0 * M_PI * (double)gf[0] * F_PARAM;
    const double grv = (double)gr[0];
    const double al  = (double)alpha[0];
    const double gn  = (double)gain[0];

    double A[4][4] = {
        { -w, 0.0, 0.0, -4.0 * w * grv * R_PARAM },
        {  w,  -w, 0.0, 0.0 },
        { 0.0,  w,  -w, 0.0 },
        { 0.0, 0.0,  w,  -w }
    };

    double kA2[4][4];
    for (int i = 0; i < 4; ++i)
        for (int j = 0; j < 4; ++j) kA2[i][j] = 0.5 * k * A[i][j];

    double Mlhs[4][4];
    for (int i = 0; i < 4; ++i)
        for (int j = 0; j < 4; ++j)
            Mlhs[i][j] = ((i == j) ? 1.0 : 0.0) - kA2[i][j] * al;

    double Minv[4][4];
    inv4x4(Mlhs, Minv);

    double Mfwd[4][4];
    for (int i = 0; i < 4; ++i)
        for (int j = 0; j < 4; ++j)
            Mfwd[i][j] = ((i == j) ? 1.0 : 0.0) + kA2[i][j] * (2.0 - al);

    double Mc[4][4];
    for (int i = 0; i < 4; ++i)
        for (int j = 0; j < 4; ++j) {
            double s = 0.0;
            for (int m = 0; m < 4; ++m) s += Minv[i][m] * Mfwd[m][j];
            Mc[i][j] = s;
        }

    double kb2_0 = 0.5 * k * w;
    double ba0  = kb2_0 * al;
    double b1m0 = kb2_0 * (1.0 - 0.5 * al);

    for (int i = 0; i < 4; ++i) {
        for (int j = 0; j < 4; ++j) c[4 * i + j] = (float)Mc[i][j];
        c[16 + i] = (float)(Minv[i][0] * ba0);
        c[20 + i] = (float)(Minv[i][0] * b1m0);
    }
    c[24] = (float)gn;
}

// Standalone prologue kernel (only used by the B%4!=0 fallback path).
__global__ void moog_prologue(const float* __restrict__ gf,
                              const float* __restrict__ gr,
                              const float* __restrict__ gain,
                              const float* __restrict__ alpha,
                              float* __restrict__ ws) {
    build_coeffs(gf, gr, gain, alpha, ws);
}

// ---------------------------------------------------------------------------
// v5 fused main: v3's verified body (all streams 16 B/lane, LDS redistribution,
// NT stores) with the coefficient build merged in. Lane 0 of each block runs
// the double-precision build AFTER the global loads are issued, so the ~2k-cycle
// double math hides under the first memory latency. No prologue launch, no ws
// round-trip.
// out layout: [0,B) = y_n ; [B,5B) = x_n ; [5B,6B) = u_n copy
// Requires B % 4 == 0. Block of 256 threads handles 1024 samples.
// ---------------------------------------------------------------------------
__global__ __launch_bounds__(256) void moog_fused(
        const f32x4* __restrict__ u4,
        const f32x4* __restrict__ x4,
        const f32x4* __restrict__ u14,
        const float* __restrict__ gf,
        const float* __restrict__ gr,
        const float* __restrict__ gain,
        const float* __restrict__ alpha,
        float* __restrict__ out,
        int B) {
    __shared__ float c[25];
    __shared__ float su[1024];
    __shared__ float su1[1024];
    __shared__ float sy[1024];

    int t = threadIdx.x;
    int nq = B >> 2;
    int qb = blockIdx.x << 8;
    int q  = qb + t;
    bool valid = q < nq;

    // Issue global loads first (independent of c).
    f32x4 u, u1;
    if (valid) {
        u  = u4[q];
        u1 = u14[q];
    }

    // Lane 0 builds the coefficients while the loads are in flight.
    if (t == 0) build_coeffs(gf, gr, gain, alpha, c);

    f32x4* ou = (f32x4*)(out + 5 * (size_t)B);
    if (valid) {
        *(f32x4*)&su[4 * t]  = u;
        *(f32x4*)&su1[4 * t] = u1;
        __builtin_nontemporal_store(u, &ou[q]);   // u_n passthrough
    }
    __syncthreads();

    int sbase = qb << 2;
    f32x4* ox = (f32x4*)(out + (size_t)B);

    #pragma unroll
    for (int k = 0; k < 4; ++k) {
        int idx = (k << 8) + t;
        int s = sbase + idx;
        if (s < B) {
            f32x4 x = x4[s];
            float uu  = su[idx];
            float uu1 = su1[idx];

            // Expression order identical to the verified kernel.
            float r0 = c[0]  * x.x + c[1]  * x.y + c[2]  * x.z + c[3]  * x.w + c[16] * uu + c[20] * uu1;
            float r1 = c[4]  * x.x + c[5]  * x.y + c[6]  * x.z + c[7]  * x.w + c[17] * uu + c[21] * uu1;
            float r2 = c[8]  * x.x + c[9]  * x.y + c[10] * x.z + c[11] * x.w + c[18] * uu + c[22] * uu1;
            float r3 = c[12] * x.x + c[13] * x.y + c[14] * x.z + c[15] * x.w + c[19] * uu + c[23] * uu1;

            f32x4 xv = {r0, r1, r2, r3};
            __builtin_nontemporal_store(xv, &ox[s]);
            sy[idx] = c[24] * r3;
        }
    }
    __syncthreads();

    if (valid) {
        f32x4 yq = *(f32x4*)&sy[4 * t];
        __builtin_nontemporal_store(yq, &((f32x4*)out)[q]);
    }
}

// ---------------------------------------------------------------------------
// Scalar fallback (the original verified kernel) for B % 4 != 0.
// ---------------------------------------------------------------------------
__global__ __launch_bounds__(256) void moog_main(
        const float*  __restrict__ u_n,
        const float4* __restrict__ x_n1,
        const float*  __restrict__ u_n1,
        const float*  __restrict__ ws,
        float* __restrict__ out,
        int B) {
    __shared__ float c[25];
    int t = threadIdx.x;
    if (t < 25) c[t] = ws[t];
    __syncthreads();

    int i = blockIdx.x * blockDim.x + t;
    if (i >= B) return;

    float4 x = x_n1[i];
    float u  = u_n[i];
    float u1 = u_n1[i];

    float r0 = c[0]  * x.x + c[1]  * x.y + c[2]  * x.z + c[3]  * x.w + c[16] * u + c[20] * u1;
    float r1 = c[4]  * x.x + c[5]  * x.y + c[6]  * x.z + c[7]  * x.w + c[17] * u + c[21] * u1;
    float r2 = c[8]  * x.x + c[9]  * x.y + c[10] * x.z + c[11] * x.w + c[18] * u + c[22] * u1;
    float r3 = c[12] * x.x + c[13] * x.y + c[14] * x.z + c[15] * x.w + c[19] * u + c[23] * u1;

    out[i] = c[24] * r3;
    float* ox = out + (size_t)B + 4 * (size_t)i;
    ox[0] = r0; ox[1] = r1; ox[2] = r2; ox[3] = r3;
    out[5 * (size_t)B + i] = u;
}

extern "C" void kernel_launch(void* const* d_in, const int* in_sizes, int n_in,
                              void* d_out, int out_size, void* d_ws, size_t ws_size,
                              hipStream_t stream) {
    const float* u_n   = (const float*)d_in[0];
    const float* x_n1  = (const float*)d_in[1];
    const float* u_n1  = (const float*)d_in[2];
    const float* gf    = (const float*)d_in[3];
    const float* gr    = (const float*)d_in[4];
    const float* gain  = (const float*)d_in[5];
    const float* alpha = (const float*)d_in[6];

    int B = in_sizes[0];

    if ((B & 3) == 0) {
        int nq = B >> 2;
        int grid = (nq + 255) / 256;   // 1024 samples per block
        moog_fused<<<grid, 256, 0, stream>>>((const f32x4*)u_n, (const f32x4*)x_n1,
                                             (const f32x4*)u_n1,
                                             gf, gr, gain, alpha,
                                             (float*)d_out, B);
    } else {
        float* ws = (float*)d_ws;
        moog_prologue<<<1, 1, 0, stream>>>(gf, gr, gain, alpha, ws);
        int block = 256;
        int grid = (B + block - 1) / block;
        moog_main<<<grid, block, 0, stream>>>(u_n, (const float4*)x_n1, u_n1, ws,
                                              (float*)d_out, B);
    }
}

// Round 6
// 191.935 us; speedup vs baseline: 1.0583x; 1.0421x over previous
//
#include <hip/hip_runtime.h>
#include <math.h>

#define SAMPLE_RATE 44100.0
#define R_PARAM 0.5
#define F_PARAM 1000.0

// ---------------------------------------------------------------------------
// Prologue: single thread builds the combined affine map from the 4 scalars.
// ws layout (floats): [0..15] Mc = M_inv@M_fwd (row-major),
//                     [16..19] va = M_inv@b_a, [20..23] vb = M_inv@b_1ma,
//                     [24] gain
// ---------------------------------------------------------------------------
__device__ void inv4x4(const double A[4][4], double Ainv[4][4]) {
    double M[4][8];
    for (int i = 0; i < 4; ++i) {
        for (int j = 0; j < 4; ++j) { M[i][j] = A[i][j]; M[i][4 + j] = (i == j) ? 1.0 : 0.0; }
    }
    for (int col = 0; col < 4; ++col) {
        int p = col;
        for (int r = col + 1; r < 4; ++r)
            if (fabs(M[r][col]) > fabs(M[p][col])) p = r;
        if (p != col)
            for (int j = 0; j < 8; ++j) { double t = M[col][j]; M[col][j] = M[p][j]; M[p][j] = t; }
        double d = 1.0 / M[col][col];
        for (int j = 0; j < 8; ++j) M[col][j] *= d;
        for (int r = 0; r < 4; ++r) {
            if (r == col) continue;
            double f = M[r][col];
            for (int j = 0; j < 8; ++j) M[r][j] -= f * M[col][j];
        }
    }
    for (int i = 0; i < 4; ++i)
        for (int j = 0; j < 4; ++j) Ainv[i][j] = M[i][4 + j];
}

__global__ void moog_prologue(const float* __restrict__ gf,
                              const float* __restrict__ gr,
                              const float* __restrict__ gain,
                              const float* __restrict__ alpha,
                              float* __restrict__ ws) {
    const double k  = 1.0 / SAMPLE_RATE;
    const double w  = 2.0 * M_PI * (double)gf[0] * F_PARAM;
    const double grv = (double)gr[0];
    const double al  = (double)alpha[0];
    const double gn  = (double)gain[0];

    double A[4][4] = {
        { -w, 0.0, 0.0, -4.0 * w * grv * R_PARAM },
        {  w,  -w, 0.0, 0.0 },
        { 0.0,  w,  -w, 0.0 },
        { 0.0, 0.0,  w,  -w }
    };

    double kA2[4][4];
    for (int i = 0; i < 4; ++i)
        for (int j = 0; j < 4; ++j) kA2[i][j] = 0.5 * k * A[i][j];

    // I - kA2*alpha
    double Mlhs[4][4];
    for (int i = 0; i < 4; ++i)
        for (int j = 0; j < 4; ++j)
            Mlhs[i][j] = ((i == j) ? 1.0 : 0.0) - kA2[i][j] * al;

    double Minv[4][4];
    inv4x4(Mlhs, Minv);

    // M_fwd = I + 2*kA2 - kA2*alpha = I + kA2*(2 - alpha)
    double Mfwd[4][4];
    for (int i = 0; i < 4; ++i)
        for (int j = 0; j < 4; ++j)
            Mfwd[i][j] = ((i == j) ? 1.0 : 0.0) + kA2[i][j] * (2.0 - al);

    // Mc = Minv @ Mfwd
    double Mc[4][4];
    for (int i = 0; i < 4; ++i)
        for (int j = 0; j < 4; ++j) {
            double s = 0.0;
            for (int m = 0; m < 4; ++m) s += Minv[i][m] * Mfwd[m][j];
            Mc[i][j] = s;
        }

    // b vectors: kb2 = k*Bv/2 with Bv = [w,0,0,0]^T
    double kb2_0 = 0.5 * k * w;
    double ba0  = kb2_0 * al;                 // b_a   = kb2*alpha
    double b1m0 = kb2_0 * (1.0 - 0.5 * al);   // b_1ma = kb2*(1 - alpha/2)

    // va = Minv @ b_a (only first component of b nonzero), vb likewise
    for (int i = 0; i < 4; ++i) {
        for (int j = 0; j < 4; ++j) ws[4 * i + j] = (float)Mc[i][j];
        ws[16 + i] = (float)(Minv[i][0] * ba0);
        ws[20 + i] = (float)(Minv[i][0] * b1m0);
    }
    ws[24] = (float)gn;
}

// ---------------------------------------------------------------------------
// Main kernel: one thread per sample. (Empirically the best structure:
// matched or beat every vectorized/redistributed/fill-shaped variant —
// the ~59 µs wall is memory-system-side, not kernel-shape-side.)
// out layout: [0,B) = y_n ; [B,5B) = x_n (4 per sample) ; [5B,6B) = u_n copy
// ---------------------------------------------------------------------------
__global__ __launch_bounds__(256) void moog_main(
        const float*  __restrict__ u_n,
        const float4* __restrict__ x_n1,
        const float*  __restrict__ u_n1,
        const float*  __restrict__ ws,
        float* __restrict__ out,
        int B) {
    __shared__ float c[25];
    int t = threadIdx.x;
    if (t < 25) c[t] = ws[t];
    __syncthreads();

    int i = blockIdx.x * blockDim.x + t;
    if (i >= B) return;

    float4 x = x_n1[i];
    float u  = u_n[i];
    float u1 = u_n1[i];

    float r0 = c[0]  * x.x + c[1]  * x.y + c[2]  * x.z + c[3]  * x.w + c[16] * u + c[20] * u1;
    float r1 = c[4]  * x.x + c[5]  * x.y + c[6]  * x.z + c[7]  * x.w + c[17] * u + c[21] * u1;
    float r2 = c[8]  * x.x + c[9]  * x.y + c[10] * x.z + c[11] * x.w + c[18] * u + c[22] * u1;
    float r3 = c[12] * x.x + c[13] * x.y + c[14] * x.z + c[15] * x.w + c[19] * u + c[23] * u1;

    out[i] = c[24] * r3;                         // y_n
    float4* ox = (float4*)(out + B);             // x_n block (16-byte aligned: B*4 bytes)
    ox[i] = make_float4(r0, r1, r2, r3);
    out[5 * (size_t)B + i] = u;                  // u_n passthrough
}

extern "C" void kernel_launch(void* const* d_in, const int* in_sizes, int n_in,
                              void* d_out, int out_size, void* d_ws, size_t ws_size,
                              hipStream_t stream) {
    const float* u_n   = (const float*)d_in[0];
    const float* x_n1  = (const float*)d_in[1];
    const float* u_n1  = (const float*)d_in[2];
    const float* gf    = (const float*)d_in[3];
    const float* gr    = (const float*)d_in[4];
    const float* gain  = (const float*)d_in[5];
    const float* alpha = (const float*)d_in[6];

    int B = in_sizes[0];
    float* ws = (float*)d_ws;

    moog_prologue<<<1, 1, 0, stream>>>(gf, gr, gain, alpha, ws);

    int block = 256;
    int grid = (B + block - 1) / block;
    moog_main<<<grid, block, 0, stream>>>(u_n, (const float4*)x_n1, u_n1, ws,
                                          (float*)d_out, B);
}